// Round 8
// baseline (903.540 us; speedup 1.0000x reference)
//
#include <hip/hip_runtime.h>
#include <math.h>

#define B_ 4
#define L_ 2048
#define S_ 2048
#define H_ 8
#define E_ 64
#define BH_ (B_*H_)
#define EPS 1e-6f
#define NBLK 1024

typedef __attribute__((ext_vector_type(8))) short short8;
typedef __attribute__((ext_vector_type(4))) float f32x4;

__device__ __forceinline__ unsigned short f2bf(float f) {
    unsigned int u = __float_as_uint(f);
    u = (u + 0x7fffu + ((u >> 16) & 1u)) >> 16;   // RNE
    return (unsigned short)u;
}

__device__ __forceinline__ float bf2f(unsigned short u) {
    return __uint_as_float(((unsigned int)u) << 16);
}

__device__ __forceinline__ float fast_tanh(float x) {
    float e = __expf(2.0f * x);
    return 1.0f - 2.0f / (e + 1.0f);
}

// XOR-swizzled LDS byte offset: rows of 128B, 16B chunks swizzled by row&7.
__device__ __forceinline__ int swb(int row, int byteoff) {
    return row * 128 + ((((byteoff >> 4) ^ (row & 7)) << 4) | (byteoff & 15));
}

// Software grid barrier, robust to arbitrary initial memory contents:
// each phase uses a distinct MAGIC; block writes slots[blk]=MAGIC, block 0
// polls all slots then releases via flag=MAGIC. Device-scope atomics + fences
// (per-XCD L2s are not coherent). Requires all blocks co-resident:
// grid=1024, launch_bounds(256,4), LDS 25KB -> 4 blocks/CU guaranteed.
__device__ __forceinline__ void gbarrier(unsigned int* slots, unsigned int* flag,
                                         unsigned int magic) {
    __syncthreads();
    __threadfence();
    if (threadIdx.x == 0)
        __hip_atomic_store(&slots[blockIdx.x], magic, __ATOMIC_RELEASE,
                           __HIP_MEMORY_SCOPE_AGENT);
    if (blockIdx.x == 0) {
        for (int i = threadIdx.x; i < NBLK; i += 256) {
            while (__hip_atomic_load(&slots[i], __ATOMIC_ACQUIRE,
                                     __HIP_MEMORY_SCOPE_AGENT) != magic)
                __builtin_amdgcn_s_sleep(2);
        }
        __syncthreads();
        if (threadIdx.x == 0)
            __hip_atomic_store(flag, magic, __ATOMIC_RELEASE,
                               __HIP_MEMORY_SCOPE_AGENT);
    }
    if (threadIdx.x == 0) {
        while (__hip_atomic_load(flag, __ATOMIC_ACQUIRE,
                                 __HIP_MEMORY_SCOPE_AGENT) != magic)
            __builtin_amdgcn_s_sleep(2);
    }
    __threadfence();
    __syncthreads();
}

// ---------------------------------------------------------------------------
// ONE kernel, 1024 blocks x 256 threads, 4 blocks/CU co-resident.
// phase 1: pre   — q/k transform -> qt,kt bf16; v -> frag-tiled vt
// phase 2: gramp — blocks 0..511: partial Gram (f32) + partial ksum
// phase 3: gramr — blocks 0..255: reduce -> Gb bf16 + ksum f32
// phase 4: attn  — 64 q-rows/block (R6 body, g-loop dropped), K LDS dbuf,
//                  frag-tiled V direct, wave-private P, in-block alpha.
// ---------------------------------------------------------------------------
__global__ __launch_bounds__(256, 4) void fused_kernel(
    const float* __restrict__ xq, const float* __restrict__ xk,
    const float* __restrict__ xv,
    const float* __restrict__ dwp, const float* __restrict__ dpp,
    unsigned short* __restrict__ qt, unsigned short* __restrict__ kt,
    unsigned short* __restrict__ vt,
    float* __restrict__ Gp, float* __restrict__ ksump,
    unsigned short* __restrict__ Gb, float* __restrict__ ksum,
    unsigned int* __restrict__ slots, unsigned int* __restrict__ flag,
    float* __restrict__ out)
{
    __shared__ __align__(16) char lds[25088];
    const int blk = blockIdx.x;
    const int tid = threadIdx.x;
    const int lane = tid & 63;
    const int w = tid >> 6;
    const int m = lane & 15;
    const int quad = lane >> 4;

    // ================= phase 1: pre =================
    {
        float dwv = dwp[0], dpv = dpp[0];
#pragma unroll
        for (int i = 0; i < 4; ++i) {
            int bx = blk * 4 + i;                  // [0,4096)
            const float* x = (bx < 2048) ? xq : xk;
            unsigned short* xt = (bx < 2048) ? qt : kt;
            int g = (bx & 2047) * 256 + tid;       // over B*L*E = 524288
            int e = g & 63;
            int bl = g >> 6;
            int b = bl >> 11;
            int l = bl & 2047;
            size_t base = (size_t)bl * (H_ * E_) + e;
            float v[8], s = 0.f, q = 0.f;
#pragma unroll
            for (int h = 0; h < 8; ++h) {
                float t = x[base + h * E_];
                v[h] = t; s += t; q += t * t;
            }
            float mean = s * 0.125f;
            float var = (q - s * mean) * (1.f / 7.f);   // ddof=1, N=8
            var = fmaxf(var, 0.f);
            float inv = 1.f / (sqrtf(var) + EPS);
            float wsc = dwv * inv;
#pragma unroll
            for (int h = 0; h < 8; ++h) {
                float t = fast_tanh(v[h] * wsc) * dpv;
                xt[((size_t)(b * H_ + h) * L_ + l) * E_ + e] = f2bf(t);
            }
        }
        // one vtrans unit per block: 64x64 tile -> frag-tiled vt
        float* lsf = (float*)lds;                  // [64][65] f32 = 16640B
        int s0v = (blk & 31) * 64;
        int h = (blk >> 5) & 7, b = blk >> 8;
#pragma unroll
        for (int j = 0; j < 4; ++j) {
            int idx = tid + j * 256;
            int r = idx >> 4, c4 = (idx & 15) * 4;
            const float4 f = *(const float4*)&xv[((size_t)(b * S_ + s0v + r) * H_ + h) * E_ + c4];
            lsf[r * 65 + c4] = f.x; lsf[r * 65 + c4 + 1] = f.y;
            lsf[r * 65 + c4 + 2] = f.z; lsf[r * 65 + c4 + 3] = f.w;
        }
        __syncthreads();
        size_t ob = ((size_t)(b * H_ + h) * (S_ / 64) + (s0v >> 6)) * 4096;
#pragma unroll
        for (int j = 0; j < 2; ++j) {
            int ri = tid + j * 256;                // ri = et*128+c*64+quad*16+m
            int et = ri >> 7, c = (ri >> 6) & 1, qd = (ri >> 4) & 3, mm = ri & 15;
            int e = et * 16 + mm, sb = c * 32 + qd * 8;
            unsigned short tmp[8];
#pragma unroll
            for (int jj = 0; jj < 8; ++jj) tmp[jj] = f2bf(lsf[(sb + jj) * 65 + e]);
            *(uint4*)&vt[ob + (size_t)ri * 8] = *(uint4*)tmp;
        }
    }
    gbarrier(slots, flag, 0x13570001u);

    // ================= phase 2: gramp (blocks 0..511) =================
    if (blk < 512) {
        unsigned short* ks = (unsigned short*)lds;     // 128*72 u16 = 18432B
        int bh = blk >> 4, sc = blk & 15;
        const unsigned short* src = kt + ((size_t)bh * S_ + sc * 128) * E_;
#pragma unroll
        for (int i = 0; i < 4; ++i) {
            int u = tid + i * 256;                 // 1024 short8 units
            *(short8*)&ks[(u >> 3) * 72 + (u & 7) * 8] = *(const short8*)(src + u * 8);
        }
        __syncthreads();
        int s0 = w * 32;
        short8 af[4];
        float ksp[4] = {0.f, 0.f, 0.f, 0.f};
#pragma unroll
        for (int i = 0; i < 4; ++i) {
            short8 a;
#pragma unroll
            for (int kk = 0; kk < 8; ++kk) {
                unsigned short uv = ks[(s0 + quad * 8 + kk) * 72 + i * 16 + m];
                a[kk] = (short)uv;
                ksp[i] += bf2f(uv);
            }
            af[i] = a;
        }
        __syncthreads();                           // all done reading ks
        float* gs = (float*)lds;                   // alias: 4096 f32 = 16384B
        float* kss = (float*)(lds + 16384);        // 64 f32
        f32x4 acc[4][4];
#pragma unroll
        for (int i = 0; i < 4; ++i)
#pragma unroll
            for (int j = 0; j < 4; ++j) {
                acc[i][j] = (f32x4){0.f, 0.f, 0.f, 0.f};
                acc[i][j] = __builtin_amdgcn_mfma_f32_16x16x32_bf16(af[i], af[j], acc[i][j], 0, 0, 0);
            }
#pragma unroll
        for (int i = 0; i < 4; ++i) {
            ksp[i] += __shfl_xor(ksp[i], 16);
            ksp[i] += __shfl_xor(ksp[i], 32);
        }
        for (int w2 = 0; w2 < 4; ++w2) {
            if (w == w2) {
#pragma unroll
                for (int i = 0; i < 4; ++i)
#pragma unroll
                    for (int j = 0; j < 4; ++j)
#pragma unroll
                        for (int r = 0; r < 4; ++r) {
                            int idx = (i * 16 + quad * 4 + r) * 64 + j * 16 + m;
                            if (w2 == 0) gs[idx] = acc[i][j][r]; else gs[idx] += acc[i][j][r];
                        }
                if (lane < 16) {
#pragma unroll
                    for (int i = 0; i < 4; ++i) {
                        int e = i * 16 + lane;
                        if (w2 == 0) kss[e] = ksp[i]; else kss[e] += ksp[i];
                    }
                }
            }
            __syncthreads();
        }
#pragma unroll
        for (int ii = 0; ii < 16; ++ii) {
            int idx = tid + ii * 256;
            Gp[(size_t)blk * 4096 + idx] = gs[idx];
        }
        if (tid < 64) ksump[blk * 64 + tid] = kss[tid];
    }
    gbarrier(slots, flag, 0x13570002u);

    // ================= phase 3: gramr (blocks 0..255) =================
    if (blk < 256) {
        int bh = blk >> 3, c = blk & 7;
        int idx = c * 512 + tid * 2;
        float s0 = 0.f, s1 = 0.f;
#pragma unroll
        for (int p = 0; p < 16; ++p) {
            const float* g = Gp + ((size_t)(bh * 16 + p)) * 4096 + idx;
            s0 += g[0]; s1 += g[1];
        }
        unsigned int pk = (unsigned int)f2bf(s0) | ((unsigned int)f2bf(s1) << 16);
        *(unsigned int*)&Gb[(size_t)bh * 4096 + idx] = pk;
        if (c == 0 && tid < 64) {
            float s = 0.f;
#pragma unroll
            for (int p = 0; p < 16; ++p) s += ksump[(bh * 16 + p) * 64 + tid];
            ksum[bh * 64 + tid] = s;
        }
    }
    gbarrier(slots, flag, 0x13570003u);

    // ================= phase 4: attn (64 q-rows/block) =================
    {
        char* ptb = lds + 16384 + w * 2048;            // wave-private P: 16x128B
        float2* ascr = (float2*)(lds + 24576) + w * 16;

        int bh = (blk & 7) * 4 + ((blk >> 3) & 3);     // XCD swizzle
        int l0 = (blk >> 5) * 64;
        int b = bh >> 3, h = bh & 7;

        const unsigned short* qtb = qt + (size_t)bh * L_ * E_;
        const unsigned short* ktb = kt + (size_t)bh * S_ * E_;
        const unsigned short* vtb = vt + (size_t)bh * (S_ / 64) * 4096;

        short8 qf[2];
#pragma unroll
        for (int c = 0; c < 2; ++c)
            qf[c] = *(const short8*)(qtb + (size_t)(l0 + w * 16 + m) * E_ + c * 32 + quad * 8);

        // in-block alpha via Gram quadratic form (R6 numerics)
        float al, alm;
        {
            const unsigned short* gb = Gb + (size_t)bh * 4096;
            float ksl[4];
#pragma unroll
            for (int j = 0; j < 4; ++j) ksl[j] = ksum[bh * 64 + j * 16 + m];
            f32x4 accj[4];
#pragma unroll
            for (int j = 0; j < 4; ++j) {
                accj[j] = (f32x4){0.f, 0.f, 0.f, 0.f};
#pragma unroll
                for (int c = 0; c < 2; ++c) {
                    short8 gf = *(const short8*)(gb + (size_t)(j * 16 + m) * 64 + c * 32 + quad * 8);
                    accj[j] = __builtin_amdgcn_mfma_f32_16x16x32_bf16(qf[c], gf, accj[j], 0, 0, 0);
                }
            }
            float ps[4] = {0, 0, 0, 0}, pr[4] = {0, 0, 0, 0};
#pragma unroll
            for (int r = 0; r < 4; ++r)
#pragma unroll
                for (int j = 0; j < 4; ++j) {
                    float qv = bf2f(qtb[(size_t)(l0 + w * 16 + quad * 4 + r) * E_ + j * 16 + m]);
                    ps[r] = fmaf(accj[j][r], qv, ps[r]);
                    pr[r] = fmaf(qv, ksl[j], pr[r]);
                }
#pragma unroll
            for (int mask = 1; mask < 16; mask <<= 1)
#pragma unroll
                for (int r = 0; r < 4; ++r) {
                    ps[r] += __shfl_xor(ps[r], mask);
                    pr[r] += __shfl_xor(pr[r], mask);
                }
            if (m == 0) {
#pragma unroll
                for (int r = 0; r < 4; ++r) {
                    float sum = pr[r];
                    float mu = sum * (1.f / S_);
                    float var = (ps[r] - sum * mu) * (1.f / (S_ - 1));   // ddof=1
                    var = fmaxf(var, 0.f);
                    float tau = sqrtf(var + EPS);
                    float a = 0.125f / tau;                               // scale=1/8
                    ascr[quad * 4 + r] = make_float2(a, a * mu);
                }
            }
            float2 a2 = ascr[m];                   // wave-private; lgkm-ordered
            al = a2.x; alm = a2.y;
        }

        float dsum = 0.f;
        f32x4 oacc[4];
#pragma unroll
        for (int et = 0; et < 4; ++et) oacc[et] = (f32x4){0.f, 0.f, 0.f, 0.f};

        // preload K tile 0 (8KB = 512 short8; 2 per thread)
        uint4 kr[2];
#pragma unroll
        for (int i = 0; i < 2; ++i)
            kr[i] = *(const uint4*)(ktb + (size_t)(tid + i * 256) * 8);
        __syncthreads();                           // LDS handoff from alpha use
#pragma unroll
        for (int i = 0; i < 2; ++i) {
            int u = tid + i * 256;
            *(uint4*)(lds + swb(u >> 3, (u & 7) * 16)) = kr[i];
        }
        __syncthreads();

        for (int st = 0; st < S_ / 64; ++st) {
            char* kcur = lds + (st & 1) * 8192;
            char* knxt = lds + ((st + 1) & 1) * 8192;
            if (st < S_ / 64 - 1) {
#pragma unroll
                for (int i = 0; i < 2; ++i)
                    kr[i] = *(const uint4*)(ktb + (size_t)(st + 1) * 4096 + (size_t)(tid + i * 256) * 8);
            }
            const unsigned short* vstb = vtb + (size_t)st * 4096;
            short8 vf[2][4];
#pragma unroll
            for (int c = 0; c < 2; ++c)
#pragma unroll
                for (int et = 0; et < 4; ++et)
                    vf[c][et] = *(const short8*)(vstb + et * 1024 + c * 512 + lane * 8);

#pragma unroll
            for (int nt = 0; nt < 4; ++nt) {
                short8 kf0 = *(const short8*)(kcur + swb(nt * 16 + m, quad * 16));
                short8 kf1 = *(const short8*)(kcur + swb(nt * 16 + m, 64 + quad * 16));
                f32x4 acc = {0.f, 0.f, 0.f, 0.f};
                acc = __builtin_amdgcn_mfma_f32_16x16x32_bf16(kf0, qf[0], acc, 0, 0, 0);
                acc = __builtin_amdgcn_mfma_f32_16x16x32_bf16(kf1, qf[1], acc, 0, 0, 0);
                unsigned int u0, u1, u2, u3;
                {
                    float p0 = __expf(fmaf(al, acc[0], -alm));
                    float p1 = __expf(fmaf(al, acc[1], -alm));
                    float p2 = __expf(fmaf(al, acc[2], -alm));
                    float p3 = __expf(fmaf(al, acc[3], -alm));
                    u0 = __float_as_uint(p0) & 0xffff0000u;
                    u1 = __float_as_uint(p1) & 0xffff0000u;
                    u2 = __float_as_uint(p2) & 0xffff0000u;
                    u3 = __float_as_uint(p3) & 0xffff0000u;
                    dsum += __uint_as_float(u0) + __uint_as_float(u1)
                          + __uint_as_float(u2) + __uint_as_float(u3);
                }
                uint2 pk;
                pk.x = (u0 >> 16) | u1;
                pk.y = (u2 >> 16) | u3;
                *(uint2*)(ptb + swb(m, nt * 32 + quad * 8)) = pk;
            }
            short8 pf0 = *(const short8*)(ptb + swb(m, quad * 16));
            short8 pf1 = *(const short8*)(ptb + swb(m, 64 + quad * 16));
#pragma unroll
            for (int et = 0; et < 4; ++et) {
                oacc[et] = __builtin_amdgcn_mfma_f32_16x16x32_bf16(pf0, vf[0][et], oacc[et], 0, 0, 0);
                oacc[et] = __builtin_amdgcn_mfma_f32_16x16x32_bf16(pf1, vf[1][et], oacc[et], 0, 0, 0);
            }
            if (st < S_ / 64 - 1) {
#pragma unroll
                for (int i = 0; i < 2; ++i) {
                    int u = tid + i * 256;
                    *(uint4*)(knxt + swb(u >> 3, (u & 7) * 16)) = kr[i];
                }
            }
            __syncthreads();
        }

        dsum += __shfl_xor(dsum, 16);
        dsum += __shfl_xor(dsum, 32);
#pragma unroll
        for (int r = 0; r < 4; ++r) {
            float dn = __shfl(dsum, quad * 4 + r);
            float rd = 1.0f / dn;
            size_t row = (size_t)(b * L_ + l0 + w * 16 + quad * 4 + r);
#pragma unroll
            for (int et = 0; et < 4; ++et)
                out[(row * H_ + h) * E_ + et * 16 + m] = oacc[et][r] * rd;
        }
    }
}

extern "C" void kernel_launch(void* const* d_in, const int* in_sizes, int n_in,
                              void* d_out, int out_size, void* d_ws, size_t ws_size,
                              hipStream_t stream)
{
    const float* q = (const float*)d_in[0];
    const float* k = (const float*)d_in[1];
    const float* v = (const float*)d_in[2];
    // d_in[3] = attn_mask (unused)
    const float* dw = (const float*)d_in[4];
    const float* dp = (const float*)d_in[5];
    float* out = (float*)d_out;

    unsigned short* qt = (unsigned short*)d_ws;              // [B,H,L,E] bf16, 8MB
    unsigned short* kt = qt + (size_t)BH_ * L_ * E_;         // [B,H,S,E] bf16, 8MB
    unsigned short* vt = kt + (size_t)BH_ * S_ * E_;         // frag-tiled, 8MB
    unsigned short* Gb = vt + (size_t)BH_ * E_ * S_;         // [B,H,64,64] bf16
    float* ksum = (float*)(Gb + (size_t)BH_ * 4096);         // [B,H,64]
    float* Gp = ksum + BH_ * 64;                             // [512][4096] f32, 8MB
    float* ksump = Gp + (size_t)512 * 4096;                  // [512][64]
    unsigned int* slots = (unsigned int*)(ksump + 512 * 64); // [1024]
    unsigned int* flag = slots + NBLK + 64;

    fused_kernel<<<NBLK, 256, 0, stream>>>(
        q, k, v, dw, dp, qt, kt, vt, Gp, ksump, Gb, ksum, slots, flag, out);
}

// Round 9
// 222.884 us; speedup vs baseline: 4.0539x; 4.0539x over previous
//
#include <hip/hip_runtime.h>
#include <math.h>

#define B_ 4
#define L_ 2048
#define S_ 2048
#define H_ 8
#define E_ 64
#define BH_ (B_*H_)
#define EPS 1e-6f

typedef __attribute__((ext_vector_type(8))) short short8;
typedef __attribute__((ext_vector_type(4))) float f32x4;

__device__ __forceinline__ unsigned short f2bf(float f) {
    unsigned int u = __float_as_uint(f);
    u = (u + 0x7fffu + ((u >> 16) & 1u)) >> 16;   // RNE
    return (unsigned short)u;
}

__device__ __forceinline__ float bf2f(unsigned short u) {
    return __uint_as_float(((unsigned int)u) << 16);
}

__device__ __forceinline__ float fast_tanh(float x) {
    float e = __expf(2.0f * x);
    return 1.0f - 2.0f / (e + 1.0f);
}

// XOR-swizzled LDS byte offset: rows of 128B, 16B chunks swizzled by row&7.
__device__ __forceinline__ int swb(int row, int byteoff) {
    return row * 128 + ((((byteoff >> 4) ^ (row & 7)) << 4) | (byteoff & 15));
}

// ---------------------------------------------------------------------------
// Launch 1: pre. Grid 3200 blocks x 256.
//  [0,2048):    q transform -> qt [B,H,L,E] bf16
//  [2048,3072): v transpose -> vt frag-tiled bf16 (R6/R8-proven layout)
//  [3072,3200): ktrans: unit=(b, 64-s tile): k transform -> kt [B,H,S,E] bf16
//               + ktT frag-tiled (A-operand layout for Gram MFMA)
//               + ksump[b][stile][h][e] partial column sums
// transform: std over H axis (8 vals, ddof=1); tanh(x*dw/(std+eps))*dp
// ---------------------------------------------------------------------------
__global__ __launch_bounds__(256) void pre_kernel(
    const float* __restrict__ xq, const float* __restrict__ xk,
    const float* __restrict__ xv,
    const float* __restrict__ dwp, const float* __restrict__ dpp,
    unsigned short* __restrict__ qt, unsigned short* __restrict__ kt,
    unsigned short* __restrict__ vt, unsigned short* __restrict__ ktT,
    float* __restrict__ ksump)
{
    __shared__ __align__(16) char lds[33024];
    const int bx = blockIdx.x;
    const int tid = threadIdx.x;
    const float dwv = dwp[0], dpv = dpp[0];

    if (bx < 2048) {
        // ---- q transform ----
        int g = bx * 256 + tid;                   // over B*L*E = 524288
        int e = g & 63;
        int bl = g >> 6;
        int b = bl >> 11;
        int l = bl & 2047;
        size_t base = (size_t)bl * (H_ * E_) + e;
        float v[8], s = 0.f, q = 0.f;
#pragma unroll
        for (int h = 0; h < 8; ++h) {
            float t = xq[base + h * E_];
            v[h] = t; s += t; q += t * t;
        }
        float mean = s * 0.125f;
        float var = (q - s * mean) * (1.f / 7.f);  // ddof=1, N=8
        var = fmaxf(var, 0.f);
        float inv = 1.f / (sqrtf(var) + EPS);
        float wsc = dwv * inv;
#pragma unroll
        for (int h = 0; h < 8; ++h) {
            float t = fast_tanh(v[h] * wsc) * dpv;
            qt[((size_t)(b * H_ + h) * L_ + l) * E_ + e] = f2bf(t);
        }
    } else if (bx < 3072) {
        // ---- vtrans: 64x64 tile -> frag-tiled vt ----
        float* lsf = (float*)lds;                  // [64][65]
        int t2 = bx - 2048;
        int s0v = (t2 & 31) * 64;
        int h = (t2 >> 5) & 7, b = t2 >> 8;
#pragma unroll
        for (int j = 0; j < 4; ++j) {
            int idx = tid + j * 256;
            int r = idx >> 4, c4 = (idx & 15) * 4;
            const float4 f = *(const float4*)&xv[((size_t)(b * S_ + s0v + r) * H_ + h) * E_ + c4];
            lsf[r * 65 + c4] = f.x; lsf[r * 65 + c4 + 1] = f.y;
            lsf[r * 65 + c4 + 2] = f.z; lsf[r * 65 + c4 + 3] = f.w;
        }
        __syncthreads();
        size_t ob = ((size_t)(b * H_ + h) * (S_ / 64) + (s0v >> 6)) * 4096;
#pragma unroll
        for (int j = 0; j < 2; ++j) {
            int ri = tid + j * 256;                // ri = et*128+c*64+quad*16+m
            int et = ri >> 7, c = (ri >> 6) & 1, qd = (ri >> 4) & 3, mm = ri & 15;
            int e = et * 16 + mm, sb = c * 32 + qd * 8;
            unsigned short tmp[8];
#pragma unroll
            for (int jj = 0; jj < 8; ++jj) tmp[jj] = f2bf(lsf[(sb + jj) * 65 + e]);
            *(uint4*)&vt[ob + (size_t)ri * 8] = *(uint4*)tmp;
        }
    } else {
        // ---- ktrans: unit = (b, stile of 64 s) ----
        int u = bx - 3072;
        int b = u >> 5, stile = u & 31;
        int s0 = stile * 64;
        float* stdl = (float*)lds;                 // 4096 f32: wsc per (s,e)
        float* ls = (float*)(lds + 16384);         // [64][65] f32
        // step 1: per-(s,e) scale from 8-head std (ddof=1)
        for (int p = 0; p < 16; ++p) {
            int idx = tid + p * 256;
            int s = idx >> 6, e = idx & 63;
            size_t base = ((size_t)(b * S_ + s0 + s) * H_) * E_ + e;
            float sm = 0.f, sq = 0.f;
#pragma unroll
            for (int h = 0; h < 8; ++h) {
                float t = xk[base + h * E_];
                sm += t; sq += t * t;
            }
            float mean = sm * 0.125f;
            float var = (sq - sm * mean) * (1.f / 7.f);
            var = fmaxf(var, 0.f);
            stdl[idx] = dwv / (sqrtf(var) + EPS);
        }
        // step 2: per head: transform -> ls, then kt rows + ktT frags + ksump
        for (int h = 0; h < 8; ++h) {
            for (int p = 0; p < 16; ++p) {
                int idx = tid + p * 256;
                int s = idx >> 6, e = idx & 63;
                size_t base = ((size_t)(b * S_ + s0 + s) * H_ + h) * E_ + e;
                float x = fast_tanh(xk[base] * stdl[idx]) * dpv;
                ls[s * 65 + e] = x;
            }
            __syncthreads();
            size_t bh = (size_t)(b * H_ + h);
            // (a) kt rows, coalesced 16B
#pragma unroll
            for (int i = 0; i < 2; ++i) {
                int u2 = tid + i * 256;
                int row = u2 >> 3, e8 = u2 & 7;
                unsigned short tmp[8];
#pragma unroll
                for (int j = 0; j < 8; ++j) tmp[j] = f2bf(ls[row * 65 + e8 * 8 + j]);
                *(uint4*)&kt[(bh * S_ + s0 + row) * E_ + e8 * 8] = *(uint4*)tmp;
            }
            // (b) ktT frag-tiled: value[j] = kt[s = sc*32+quad*8+j][e = i*16+m]
#pragma unroll
            for (int i = 0; i < 2; ++i) {
                int ri = tid + i * 256;
                int lsc = ri >> 8, ii = (ri >> 6) & 3, ln = ri & 63;
                int qd = ln >> 4, mm = ln & 15;
                int e = ii * 16 + mm, sb = lsc * 32 + qd * 8;
                unsigned short tmp[8];
#pragma unroll
                for (int j = 0; j < 8; ++j) tmp[j] = f2bf(ls[(sb + j) * 65 + e]);
                *(uint4*)&ktT[(((bh * 64) + (size_t)(stile * 2 + lsc)) * 4 + ii) * 512 + (size_t)ln * 8] = *(uint4*)tmp;
            }
            // (c) ksum partials (column sums over the 64 s of this tile)
            if (tid < 64) {
                float sk = 0.f;
                for (int s = 0; s < 64; ++s) sk += ls[s * 65 + tid];
                ksump[(((size_t)b * 32 + stile) * 8 + h) * 64 + tid] = sk;
            }
            __syncthreads();
        }
    }
}

// ---------------------------------------------------------------------------
// Launch 2: attn. 1024 blocks x 256 thr, 4 blocks/CU.
// Prologue: kss (ksum from partials) -> per-block Gram from ktT (pure
// VMEM+MFMA, 32x redundant but fully parallel) -> 4-wave reduce into gs
// (stride-65, conflict-free) -> alpha via Gram quadratic form.
// Main loop: R8-phase-4 proven body: K LDS dbuf (1 barrier/iter), frag-tiled
// V direct from global, wave-private P, 64 q-rows/block.
// ---------------------------------------------------------------------------
__global__ __launch_bounds__(256, 4) void attn_kernel(
    const unsigned short* __restrict__ qt,
    const unsigned short* __restrict__ kt,
    const unsigned short* __restrict__ vt,
    const unsigned short* __restrict__ ktT,
    const float* __restrict__ ksump,
    float* __restrict__ out)
{
    __shared__ __align__(16) char lds[25600];
    // [0,16640)   gs (64x65 f32)  -- aliased by K dbuf [0,16384) in main loop
    // [16640,24832) ptb (4 waves x 2KB)
    // [24832,25344) ascr ; [25344,25600) kss
    const int tid = threadIdx.x;
    const int lane = tid & 63;
    const int w = tid >> 6;
    const int m = lane & 15;
    const int quad = lane >> 4;
    float* gs = (float*)lds;
    char* ptb = lds + 16640 + w * 2048;
    float2* ascr = (float2*)(lds + 24832) + w * 16;
    float* kss = (float*)(lds + 25344);

    const int blk = blockIdx.x;
    const int bh = (blk & 7) * 4 + ((blk >> 3) & 3);   // XCD swizzle
    const int l0 = (blk >> 5) * 64;
    const int b = bh >> 3, h = bh & 7;

    const unsigned short* qtb = qt + (size_t)bh * L_ * E_;
    const unsigned short* ktb = kt + (size_t)bh * S_ * E_;
    const unsigned short* vtb = vt + (size_t)bh * (S_ / 64) * 4096;
    const unsigned short* ktTb = ktT + (size_t)bh * 64 * 4 * 512;

    // ---- kss: ksum[e] from 32 partials ----
    if (tid < 64) {
        float s = 0.f;
#pragma unroll
        for (int st = 0; st < 32; ++st)
            s += ksump[(((size_t)b * 32 + st) * 8 + h) * 64 + tid];
        kss[tid] = s;
    }

    // ---- per-block Gram from ktT (VMEM+MFMA only) ----
    f32x4 acc[4][4];
#pragma unroll
    for (int i = 0; i < 4; ++i)
#pragma unroll
        for (int j = 0; j < 4; ++j) acc[i][j] = (f32x4){0.f, 0.f, 0.f, 0.f};
    for (int sc = w; sc < 64; sc += 4) {
        short8 af[4];
#pragma unroll
        for (int i = 0; i < 4; ++i)
            af[i] = *(const short8*)(ktTb + ((size_t)sc * 4 + i) * 512 + (size_t)lane * 8);
#pragma unroll
        for (int i = 0; i < 4; ++i)
#pragma unroll
            for (int j = 0; j < 4; ++j)
                acc[i][j] = __builtin_amdgcn_mfma_f32_16x16x32_bf16(af[i], af[j], acc[i][j], 0, 0, 0);
    }
    // 4-wave reduce into gs (stride 65)
    for (int w2 = 0; w2 < 4; ++w2) {
        if (w == w2) {
#pragma unroll
            for (int i = 0; i < 4; ++i)
#pragma unroll
                for (int j = 0; j < 4; ++j)
#pragma unroll
                    for (int r = 0; r < 4; ++r) {
                        int idx = (i * 16 + quad * 4 + r) * 65 + j * 16 + m;
                        if (w2 == 0) gs[idx] = acc[i][j][r]; else gs[idx] += acc[i][j][r];
                    }
        }
        __syncthreads();
    }

    // ---- Q frags + alpha via quadratic form (R6/R8-proven numerics) ----
    short8 qf[2];
#pragma unroll
    for (int c = 0; c < 2; ++c)
        qf[c] = *(const short8*)(qtb + (size_t)(l0 + w * 16 + m) * E_ + c * 32 + quad * 8);

    float al, alm;
    {
        float ksl[4];
#pragma unroll
        for (int j = 0; j < 4; ++j) ksl[j] = kss[j * 16 + m];
        f32x4 accj[4];
#pragma unroll
        for (int j = 0; j < 4; ++j) {
            accj[j] = (f32x4){0.f, 0.f, 0.f, 0.f};
#pragma unroll
            for (int c = 0; c < 2; ++c) {
                unsigned short gtmp[8];
#pragma unroll
                for (int kk = 0; kk < 8; ++kk)
                    gtmp[kk] = f2bf(gs[(j * 16 + m) * 65 + c * 32 + quad * 8 + kk]);
                short8 gf = *(short8*)gtmp;
                accj[j] = __builtin_amdgcn_mfma_f32_16x16x32_bf16(qf[c], gf, accj[j], 0, 0, 0);
            }
        }
        float ps[4] = {0, 0, 0, 0}, pr[4] = {0, 0, 0, 0};
#pragma unroll
        for (int r = 0; r < 4; ++r)
#pragma unroll
            for (int j = 0; j < 4; ++j) {
                float qv = bf2f(qtb[(size_t)(l0 + w * 16 + quad * 4 + r) * E_ + j * 16 + m]);
                ps[r] = fmaf(accj[j][r], qv, ps[r]);
                pr[r] = fmaf(qv, ksl[j], pr[r]);
            }
#pragma unroll
        for (int mask = 1; mask < 16; mask <<= 1)
#pragma unroll
            for (int r = 0; r < 4; ++r) {
                ps[r] += __shfl_xor(ps[r], mask);
                pr[r] += __shfl_xor(pr[r], mask);
            }
        if (m == 0) {
#pragma unroll
            for (int r = 0; r < 4; ++r) {
                float sum = pr[r];
                float mu = sum * (1.f / S_);
                float var = (ps[r] - sum * mu) * (1.f / (S_ - 1));   // ddof=1
                var = fmaxf(var, 0.f);
                float tau = sqrtf(var + EPS);
                float a = 0.125f / tau;                               // scale=1/8
                ascr[quad * 4 + r] = make_float2(a, a * mu);
            }
        }
        float2 a2 = ascr[m];                       // wave-private; lgkm-ordered
        al = a2.x; alm = a2.y;
    }

    float dsum = 0.f;
    f32x4 oacc[4];
#pragma unroll
    for (int et = 0; et < 4; ++et) oacc[et] = (f32x4){0.f, 0.f, 0.f, 0.f};

    // preload K tile 0 (8KB)
    uint4 kr[2];
#pragma unroll
    for (int i = 0; i < 2; ++i)
        kr[i] = *(const uint4*)(ktb + (size_t)(tid + i * 256) * 8);
    __syncthreads();                               // gs reads done -> K dbuf reuse
#pragma unroll
    for (int i = 0; i < 2; ++i) {
        int u = tid + i * 256;
        *(uint4*)(lds + swb(u >> 3, (u & 7) * 16)) = kr[i];
    }
    __syncthreads();

    for (int st = 0; st < S_ / 64; ++st) {
        char* kcur = lds + (st & 1) * 8192;
        char* knxt = lds + ((st + 1) & 1) * 8192;
        if (st < S_ / 64 - 1) {
#pragma unroll
            for (int i = 0; i < 2; ++i)
                kr[i] = *(const uint4*)(ktb + (size_t)(st + 1) * 4096 + (size_t)(tid + i * 256) * 8);
        }
        const unsigned short* vstb = vtb + (size_t)st * 4096;
        short8 vf[2][4];
#pragma unroll
        for (int c = 0; c < 2; ++c)
#pragma unroll
            for (int et = 0; et < 4; ++et)
                vf[c][et] = *(const short8*)(vstb + et * 1024 + c * 512 + lane * 8);

#pragma unroll
        for (int nt = 0; nt < 4; ++nt) {
            short8 kf0 = *(const short8*)(kcur + swb(nt * 16 + m, quad * 16));
            short8 kf1 = *(const short8*)(kcur + swb(nt * 16 + m, 64 + quad * 16));
            f32x4 acc2 = {0.f, 0.f, 0.f, 0.f};
            acc2 = __builtin_amdgcn_mfma_f32_16x16x32_bf16(kf0, qf[0], acc2, 0, 0, 0);
            acc2 = __builtin_amdgcn_mfma_f32_16x16x32_bf16(kf1, qf[1], acc2, 0, 0, 0);
            unsigned int u0, u1, u2, u3;
            {
                float p0 = __expf(fmaf(al, acc2[0], -alm));
                float p1 = __expf(fmaf(al, acc2[1], -alm));
                float p2 = __expf(fmaf(al, acc2[2], -alm));
                float p3 = __expf(fmaf(al, acc2[3], -alm));
                u0 = __float_as_uint(p0) & 0xffff0000u;
                u1 = __float_as_uint(p1) & 0xffff0000u;
                u2 = __float_as_uint(p2) & 0xffff0000u;
                u3 = __float_as_uint(p3) & 0xffff0000u;
                dsum += __uint_as_float(u0) + __uint_as_float(u1)
                      + __uint_as_float(u2) + __uint_as_float(u3);
            }
            uint2 pk;
            pk.x = (u0 >> 16) | u1;
            pk.y = (u2 >> 16) | u3;
            *(uint2*)(ptb + swb(m, nt * 32 + quad * 8)) = pk;
        }
        short8 pf0 = *(const short8*)(ptb + swb(m, quad * 16));
        short8 pf1 = *(const short8*)(ptb + swb(m, 64 + quad * 16));
#pragma unroll
        for (int et = 0; et < 4; ++et) {
            oacc[et] = __builtin_amdgcn_mfma_f32_16x16x32_bf16(pf0, vf[0][et], oacc[et], 0, 0, 0);
            oacc[et] = __builtin_amdgcn_mfma_f32_16x16x32_bf16(pf1, vf[1][et], oacc[et], 0, 0, 0);
        }
        if (st < S_ / 64 - 1) {
#pragma unroll
            for (int i = 0; i < 2; ++i) {
                int u = tid + i * 256;
                *(uint4*)(knxt + swb(u >> 3, (u & 7) * 16)) = kr[i];
            }
        }
        __syncthreads();
    }

    dsum += __shfl_xor(dsum, 16);
    dsum += __shfl_xor(dsum, 32);
#pragma unroll
    for (int r = 0; r < 4; ++r) {
        float dn = __shfl(dsum, quad * 4 + r);
        float rd = 1.0f / dn;
        size_t row = (size_t)(b * L_ + l0 + w * 16 + quad * 4 + r);
#pragma unroll
        for (int et = 0; et < 4; ++et)
            out[(row * H_ + h) * E_ + et * 16 + m] = oacc[et][r] * rd;
    }
}

extern "C" void kernel_launch(void* const* d_in, const int* in_sizes, int n_in,
                              void* d_out, int out_size, void* d_ws, size_t ws_size,
                              hipStream_t stream)
{
    const float* q = (const float*)d_in[0];
    const float* k = (const float*)d_in[1];
    const float* v = (const float*)d_in[2];
    // d_in[3] = attn_mask (unused)
    const float* dw = (const float*)d_in[4];
    const float* dp = (const float*)d_in[5];
    float* out = (float*)d_out;

    unsigned short* qt  = (unsigned short*)d_ws;               // [B,H,L,E] 8MB
    unsigned short* kt  = qt  + (size_t)BH_ * L_ * E_;         // [B,H,S,E] 8MB
    unsigned short* vt  = kt  + (size_t)BH_ * S_ * E_;         // frag-tiled 8MB
    unsigned short* ktT = vt  + (size_t)BH_ * E_ * S_;         // frag-tiled 8MB
    float* ksump = (float*)(ktT + (size_t)BH_ * S_ * E_);      // [B,32,H,64] 256KB

    pre_kernel<<<3200, 256, 0, stream>>>(q, k, v, dw, dp, qt, kt, vt, ktT, ksump);
    attn_kernel<<<1024, 256, 0, stream>>>(qt, kt, vt, ktT, ksump, out);
}